// Round 9
// baseline (464.195 us; speedup 1.0000x reference)
//
#include <hip/hip_runtime.h>
#include <math.h>

#define NCLASS  10
#define NFEAT   64
#define CHUNK   1024          // rows per hist/scatter chunk
#define NCHUNK_MAX 512        // N=524288 -> 512 chunks
#define K1D_BPC 104           // blocks per class in k1d
#define NSHARD  16            // sharded M accumulators

// ws layout (4-byte units)
#define OFF_CNT  0                         // [16] int
#define OFF_PADO 16                        // [16] int
#define OFF_LDC  32                        // [16] float
#define OFF_PM   48                        // [48] float
#define OFF_PL   96                        // [48] float
#define OFF_MU   144                       // [640] float
#define OFF_SC   784                       // [10][4096] float
#define OFF_S    41744                     // [640] float, atomic accum  (zeroed)
#define OFF_MS   42384                     // [10][16][4096] float shards (zeroed)
#define OFF_HB   697744                    // [10][512] int
#define OFF_SIDX 702864                    // [N+640] int
#define ZERO_LO  OFF_S
#define ZERO_HI  (OFF_MS + NCLASS*NSHARD*4096)

typedef short  s8v  __attribute__((ext_vector_type(8)));
typedef short  s4v  __attribute__((ext_vector_type(4)));
typedef float  f16v __attribute__((ext_vector_type(16)));

__device__ __forceinline__ float rlane(float v, int l) {
  return __int_as_float(__builtin_amdgcn_readlane(__float_as_int(v), l));
}
__device__ __forceinline__ unsigned short f2bf(float x) {   // RNE to bf16
  union { float f; unsigned u; } v; v.f = x;
  unsigned r = v.u + 0x7fffu + ((v.u >> 16) & 1u);
  return (unsigned short)(r >> 16);
}
__device__ __forceinline__ float bf2f(unsigned short b) {
  union { float f; unsigned u; } v; v.u = ((unsigned)b) << 16;
  return v.f;
}

// ---------------------------------------------------------------- k1a: zero + per-chunk hist
__global__ __launch_bounds__(256) void k1a_hist(const int* __restrict__ T,
                                                float* __restrict__ ws, int N, int nchunk) {
  const int b = blockIdx.x, t = threadIdx.x;
  for (int z = ZERO_LO + b * 256 + t; z < ZERO_HI; z += nchunk * 256) ws[z] = 0.0f;
  __shared__ int h[NCLASS];
  if (t < NCLASS) h[t] = 0;
  __syncthreads();
  int start = b * CHUNK;
#pragma unroll
  for (int u = 0; u < 4; ++u) {
    int i = start + u * 256 + t;
    if (i < N) atomicAdd(&h[T[i]], 1);
  }
  __syncthreads();
  if (t < NCLASS) ((int*)(ws + OFF_HB))[t * NCHUNK_MAX + b] = h[t];
}

// ---------------------------------------------------------------- k1b: parallel scan -> bases
__global__ __launch_bounds__(640) void k1b_scan(float* __restrict__ ws, int nchunk) {
  const int w = threadIdx.x >> 6;
  const int l = threadIdx.x & 63;
  int* Hg = (int*)(ws + OFF_HB);
  __shared__ int tot[NCLASS];
  int v[8], pre[8];
  int lanesum = 0;
#pragma unroll
  for (int u = 0; u < 8; ++u) {
    int b = l * 8 + u;
    v[u] = (b < nchunk) ? Hg[w * NCHUNK_MAX + b] : 0;
    pre[u] = lanesum;
    lanesum += v[u];
  }
  int incl = lanesum;
#pragma unroll
  for (int off = 1; off < 64; off <<= 1) {
    int t2 = __shfl_up(incl, off, 64);
    if (l >= off) incl += t2;
  }
  int excl = incl - lanesum;
  int ctot = __shfl(incl, 63, 64);
  if (l == 0) tot[w] = ctot;
  __syncthreads();
  int pado = 0;
#pragma unroll
  for (int c = 0; c < NCLASS; ++c)
    if (c < w) pado += (tot[c] + 63) & ~63;
#pragma unroll
  for (int u = 0; u < 8; ++u) {
    int b = l * 8 + u;
    if (b < nchunk) Hg[w * NCHUNK_MAX + b] = pado + excl + pre[u];
  }
  if (l == 0) {
    ((int*)(ws + OFF_CNT))[w] = ctot;
    ((int*)(ws + OFF_PADO))[w] = pado;
    if (w == NCLASS - 1) ((int*)(ws + OFF_PADO))[NCLASS] = pado + ((ctot + 63) & ~63);
  }
}

// ---------------------------------------------------------------- k1c: deterministic-base scatter
__global__ __launch_bounds__(256) void k1c_scatter(const int* __restrict__ T,
                                                   float* __restrict__ ws, int N) {
  __shared__ int lcnt[NCLASS], lbase[NCLASS];
  const int b = blockIdx.x, t = threadIdx.x;
  if (t < NCLASS) { lcnt[t] = 0; lbase[t] = ((const int*)(ws + OFF_HB))[t * NCHUNK_MAX + b]; }
  __syncthreads();
  int start = b * CHUNK;
  int tv[4], rk[4];
#pragma unroll
  for (int u = 0; u < 4; ++u) {
    int i = start + u * 256 + t;
    if (i < N) { tv[u] = T[i]; rk[u] = atomicAdd(&lcnt[tv[u]], 1); }
    else tv[u] = -1;
  }
  __syncthreads();
  int* sidx = (int*)(ws + OFF_SIDX);
#pragma unroll
  for (int u = 0; u < 4; ++u)
    if (tv[u] >= 0) sidx[lbase[tv[u]] + rk[u]] = start + u * 256 + t;
}

// ---------------------------------------------------------------- k1d: MFMA split-bf16 Gram
// G = H'H + H'L + (H'L)'  (LL ~2^-18, dropped). acc1 = H'H, acc2 = H'L:
// 8 MFMAs + 12 b128 reads per 64-row batch (was 12+16). 2-deep prefetch
// pipeline: loads for batch i+2 issued before barrier i; conversion of batch
// i+1 runs a full iteration after its loads (gather latency covered).
// Epilogue: two-phase LDS merge adds acc2^T (quadrant-disjoint), then
// coalesced global atomics into 1-of-16 shards.
__global__ __launch_bounds__(256, 4) void k1d_gram(const float* __restrict__ X,
                                                   float* __restrict__ ws) {
  __shared__ __align__(16) short Ab[2][2][64 * 72];   // [dbuf][hi/lo][feat*72+row'] 36864B
  const int c    = blockIdx.y;
  const int t    = threadIdx.x;
  const int w    = t >> 6, lane = t & 63;
  const int wi   = w >> 1, wj = w & 1;
  const int mcol = lane & 31, khalf = lane >> 5;
  const int rq   = t >> 4, fq = t & 15;      // staging: row-quad, feat-quad
  const int cnt  = ((const int*)(ws + OFF_CNT))[c];
  const int base = ((const int*)(ws + OFF_PADO))[c];
  const int* __restrict__ sidx = (const int*)(ws + OFF_SIDX);
  const float4* __restrict__ X4 = (const float4*)X;
  const int nmb = (cnt + 63) >> 6;
  const int mb0 = blockIdx.x;

  f16v acc1 = {}, acc2 = {};
  float csum[4] = {0.f, 0.f, 0.f, 0.f};
  float4 pv[2][4];

  // pipeline helpers ------------------------------------------------
  // LOAD(bi, dst): gather batch (mb0 + bi*K1D_BPC) rows into dst regs
#define LOADB(bi, dst)                                                   \
  {                                                                      \
    int b_ = mb0 + (bi) * K1D_BPC;                                       \
    _Pragma("unroll")                                                    \
    for (int j = 0; j < 4; ++j) {                                        \
      int p_ = (b_ << 6) + rq * 4 + j;                                   \
      float4 v_ = {0.f, 0.f, 0.f, 0.f};                                  \
      if (b_ < nmb && p_ < cnt) v_ = X4[(size_t)sidx[base + p_] * 16 + fq]; \
      (dst)[j] = v_;                                                     \
    }                                                                    \
  }
  // CONVB(src, dbuf): split src into bf16 hi/lo planes of Ab[dbuf]
#define CONVB(src, dbuf)                                                 \
  {                                                                      \
    short* hi_ = &Ab[dbuf][0][0];                                        \
    short* lo_ = &Ab[dbuf][1][0];                                        \
    _Pragma("unroll")                                                    \
    for (int e = 0; e < 4; ++e) {                                        \
      int f_ = fq * 4 + e;                                               \
      float x0 = (&(src)[0].x)[e], x1 = (&(src)[1].x)[e];                \
      float x2 = (&(src)[2].x)[e], x3 = (&(src)[3].x)[e];                \
      csum[e] += x0 + x1 + x2 + x3;                                      \
      unsigned short h0 = f2bf(x0), h1 = f2bf(x1), h2 = f2bf(x2), h3 = f2bf(x3); \
      s4v hv = {(short)h0, (short)h1, (short)h2, (short)h3};             \
      s4v lv = {(short)f2bf(x0 - bf2f(h0)), (short)f2bf(x1 - bf2f(h1)),  \
                (short)f2bf(x2 - bf2f(h2)), (short)f2bf(x3 - bf2f(h3))}; \
      int off_ = f_ * 72 + (((rq >> 1) ^ (f_ >> 3)) << 3) + ((rq & 1) << 2); \
      *(s4v*)(hi_ + off_) = hv;                                          \
      *(s4v*)(lo_ + off_) = lv;                                          \
    }                                                                    \
  }

  int nb_blk = (nmb > mb0) ? ((nmb - mb0 + K1D_BPC - 1) / K1D_BPC) : 0;

  // prologue: batch 0 -> buf0; batch 1 -> pv[0]
  LOADB(0, pv[0]);
  CONVB(pv[0], 0);
  LOADB(1, pv[0]);

  const int fA = wi * 32 + mcol;
  const int fB = wj * 32 + mcol;
  const int offA0 = fA * 72, offB0 = fB * 72;
  const int swA = fA >> 3, swB = fB >> 3;

  for (int i = 0; i < nb_blk; ++i) {
    LOADB(i + 2, pv[(i + 1) & 1]);          // 2-deep prefetch
    __syncthreads();                         // buf[i&1] writes visible
    {
      const short* hi = &Ab[i & 1][0][0];
      const short* lo = &Ab[i & 1][1][0];
#pragma unroll
      for (int ks = 0; ks < 4; ++ks) {
        int rb = ks * 2 + khalf;
        s8v aH = *(const s8v*)(hi + offA0 + ((rb ^ swA) << 3));
        s8v bH = *(const s8v*)(hi + offB0 + ((rb ^ swB) << 3));
        s8v bL = *(const s8v*)(lo + offB0 + ((rb ^ swB) << 3));
        acc1 = __builtin_amdgcn_mfma_f32_32x32x16_bf16(aH, bH, acc1, 0, 0, 0);
        acc2 = __builtin_amdgcn_mfma_f32_32x32x16_bf16(aH, bL, acc2, 0, 0, 0);
      }
    }
    CONVB(pv[i & 1], (i + 1) & 1);          // convert batch i+1 (loaded last iter)
  }
  __syncthreads();

  // epilogue: R = full 64x64 Gram in LDS (65-stride), colp = col-sum partials
  float* R    = (float*)&Ab[0][0][0];        // 64*65 = 4160 floats
  float* colp = R + 4224;                    // 16*64 floats
  *(float4*)&colp[rq * 64 + fq * 4] = *(float4*)csum;
  // phase 1: own quadrant gets acc1 + acc2 (HH + HL)
#pragma unroll
  for (int r = 0; r < 16; ++r) {
    int fr = wi * 32 + (r & 3) + 8 * (r >> 2) + 4 * khalf;
    R[fr * 65 + fB] = acc1[r] + acc2[r];
  }
  __syncthreads();
  // phase 2: transposed quadrant gets acc2^T (LH) — quadrant-disjoint per wave
#pragma unroll
  for (int r = 0; r < 16; ++r) {
    int fr = wi * 32 + (r & 3) + 8 * (r >> 2) + 4 * khalf;
    R[fB * 65 + fr] += acc2[r];
  }
  __syncthreads();

  float* Msh = ws + OFF_MS + (size_t)(c * NSHARD + (blockIdx.x & (NSHARD - 1))) * 4096;
  for (int e = t; e < 4096; e += 256)
    atomicAdd(&Msh[e], R[(e >> 6) * 65 + (e & 63)]);
  if (t < 64) {
    float s = 0.0f;
#pragma unroll
    for (int g = 0; g < 16; ++g) s += colp[g * 64 + t];
    atomicAdd(&ws[OFF_S + c * 64 + t], s);
  }
#undef LOADB
#undef CONVB
}

// ---------------------------------------------------------------- k1e: reduce shards -> mu, Sc
__global__ __launch_bounds__(256) void k1e_cov(float* __restrict__ ws) {
  const int c = blockIdx.x, t = threadIdx.x;
  __shared__ float mu[64];
  float cnt = (float)((const int*)(ws + OFF_CNT))[c];
  if (t < 64) {
    float m = ws[OFF_S + c * 64 + t] / cnt;
    mu[t] = m;
    ws[OFF_MU + c * 64 + t] = m;
  }
  __syncthreads();
  float inv = 1.0f / (cnt - 1.0f);
  const float* Ms = ws + OFF_MS + (size_t)c * NSHARD * 4096;
  for (int e = t; e < 4096; e += 256) {
    float s = 0.0f;
#pragma unroll
    for (int sh = 0; sh < NSHARD; ++sh) s += Ms[sh * 4096 + e];
    int r = e >> 6, l = e & 63;
    ws[OFF_SC + c * 4096 + e] = (s - cnt * mu[r] * mu[l]) * inv;
  }
}

// ---------------------------------------------------------------- k2b: register Cholesky
// R5-proven: global -> LDS tile -> float4 reg loads -> register Cholesky with
// readlane broadcasts. (Direct-global init spills S[] to scratch — keep LDS hop.)
__global__ __launch_bounds__(64) void k2b_chol(float* __restrict__ ws) {
  __shared__ float Sld[64][65];
  const int lane = threadIdx.x;
  const int bid  = blockIdx.x;

  int ci, cj, p = -1;
  bool isPair = (bid >= NCLASS);
  if (!isPair) { ci = cj = bid; }
  else {
    p = bid - NCLASS;
    int rem = p, i = 0;
    while (rem >= 9 - i) { rem -= 9 - i; ++i; }
    ci = i; cj = i + 1 + rem;
  }

  const float* A = ws + OFF_SC + ci * 4096;
  const float* B = ws + OFF_SC + cj * 4096;
  for (int r = 0; r < 64; ++r) {
    float v = A[r * 64 + lane];
    if (isPair) v = 0.5f * (v + B[r * 64 + lane]);
    Sld[r][lane] = v;
  }
  float pi = isPair ? (ws[OFF_MU + ci * 64 + lane] - ws[OFF_MU + cj * 64 + lane]) : 0.0f;
  __syncthreads();

  float S[64];
#pragma unroll
  for (int q = 0; q < 16; ++q)
    *(float4*)&S[q * 4] = *(const float4*)&Sld[lane][q * 4];

  float logacc = 0.0f, s2 = 0.0f;
#pragma unroll
  for (int k = 0; k < 64; ++k) {
    float lkk = sqrtf(rlane(S[k], k));
    float inv = 1.0f / lkk;
    float lik = S[k] * inv;
    S[k] = lik;
    logacc += logf(lkk);
    float yk = rlane(pi, k) * inv;
    s2 += yk * yk;
    pi -= (lane > k) ? lik * yk : 0.0f;
#pragma unroll
    for (int j = k + 1; j < 64; ++j)
      S[j] -= lik * rlane(lik, j);
  }

  if (lane == 0) {
    if (isPair) {
      ws[OFF_PM + p] = s2 * 0.125f;
      ws[OFF_PL + p] = 2.0f * logacc;
    } else {
      ws[OFF_LDC + bid] = 2.0f * logacc;
    }
  }
}

// ---------------------------------------------------------------- k2c: final scalar
__global__ void k2c_final(const float* __restrict__ Ksamp,
                          const float* __restrict__ ws,
                          float* __restrict__ out) {
  __shared__ float ldc[10], pm[45], pl[45];
  __shared__ float Km[100], Sp[100], L[100], Inv[100], Aa[100];
  __shared__ float red[3];
  const int tid = threadIdx.x;
  const int k = 10;

  if (tid < 3) red[tid] = 0.0f;
  if (tid < 10) ldc[tid] = ws[OFF_LDC + tid];
  if (tid < 45) { pm[tid] = ws[OFF_PM + tid]; pl[tid] = ws[OFF_PL + tid]; }
  if (tid < 100) Sp[tid] = Ksamp[tid];
  __syncthreads();

  float s00 = Sp[0];
  if (tid < 100) {
    int i = tid / 10, j = tid % 10;
    float Kv;
    if (i == j) Kv = s00;
    else {
      int a = i < j ? i : j, b = i < j ? j : i;
      int pp = (a * (19 - a)) / 2 + (b - a - 1);
      float D = pm[pp] + 0.5f * (pl[pp] - 0.5f * (ldc[i] + ldc[j]));
      Kv = s00 * 0.5f * expf(-D * D * 100.0f);
    }
    Km[tid] = Kv;
    Aa[tid] = Kv;
  }
  __syncthreads();

  for (int kk = 0; kk < k; ++kk) {
    if (tid == kk) {
      float s = Sp[kk * k + kk];
      for (int m = 0; m < kk; ++m) s -= L[kk * k + m] * L[kk * k + m];
      L[kk * k + kk] = sqrtf(s);
    }
    __syncthreads();
    if (tid > kk && tid < k) {
      float v = Sp[tid * k + kk];
      for (int m = 0; m < kk; ++m) v -= L[tid * k + m] * L[kk * k + m];
      L[tid * k + kk] = v / L[kk * k + kk];
    }
    __syncthreads();
  }
  if (tid < k) atomicAdd(&red[0], 2.0f * logf(L[tid * k + tid]));

  if (tid < k) {
    float y[10], x[10];
    for (int r = 0; r < k; ++r) {
      float v = (r == tid) ? 1.0f : 0.0f;
      for (int m = 0; m < r; ++m) v -= L[r * k + m] * y[m];
      y[r] = v / L[r * k + r];
    }
    for (int r = k - 1; r >= 0; --r) {
      float v = y[r];
      for (int m = r + 1; m < k; ++m) v -= L[m * k + r] * x[m];
      x[r] = v / L[r * k + r];
    }
    for (int r = 0; r < k; ++r) Inv[r * k + tid] = x[r];
  }
  __syncthreads();
  if (tid < 100) atomicAdd(&red[1], Inv[tid] * Km[tid]);

  for (int kk = 0; kk < k; ++kk) {
    if (tid == 0) {
      int piv = kk; float mx = fabsf(Aa[kk * k + kk]);
      for (int r = kk + 1; r < k; ++r) {
        float v = fabsf(Aa[r * k + kk]);
        if (v > mx) { mx = v; piv = r; }
      }
      if (piv != kk)
        for (int c2 = 0; c2 < k; ++c2) {
          float tmp = Aa[kk * k + c2]; Aa[kk * k + c2] = Aa[piv * k + c2]; Aa[piv * k + c2] = tmp;
        }
      red[2] += logf(fabsf(Aa[kk * k + kk]));
    }
    __syncthreads();
    if (tid < 100) {
      int r = tid / 10, c2 = tid % 10;
      if (r > kk && c2 > kk)
        Aa[r * k + c2] -= Aa[r * k + kk] / Aa[kk * k + kk] * Aa[kk * k + c2];
    }
    __syncthreads();
  }

  if (tid == 0)
    out[0] = 0.5f * (red[1] - (float)k + red[0] - red[2]);
}

// ---------------------------------------------------------------- launch
extern "C" void kernel_launch(void* const* d_in, const int* in_sizes, int n_in,
                              void* d_out, int out_size, void* d_ws, size_t ws_size,
                              hipStream_t stream) {
  const float* X  = (const float*)d_in[0];
  const int*   T  = (const int*)d_in[1];
  const float* Ks = (const float*)d_in[2];
  float* out = (float*)d_out;
  float* ws  = (float*)d_ws;
  int N = in_sizes[1];
  int nchunk = (N + CHUNK - 1) / CHUNK;

  k1a_hist<<<nchunk, 256, 0, stream>>>(T, ws, N, nchunk);
  k1b_scan<<<1, 640, 0, stream>>>(ws, nchunk);
  k1c_scatter<<<nchunk, 256, 0, stream>>>(T, ws, N);
  k1d_gram<<<dim3(K1D_BPC, NCLASS), 256, 0, stream>>>(X, ws);
  k1e_cov<<<NCLASS, 256, 0, stream>>>(ws);
  k2b_chol<<<55, 64, 0, stream>>>(ws);
  k2c_final<<<1, 128, 0, stream>>>(Ks, ws, out);
}

// Round 10
// 361.319 us; speedup vs baseline: 1.2847x; 1.2847x over previous
//
#include <hip/hip_runtime.h>
#include <math.h>

#define NCLASS  10
#define NFEAT   64
#define CHUNK   1024          // rows per hist/scatter chunk
#define NCHUNK_MAX 512        // N=524288 -> 512 chunks
#define K1D_BPC 104           // blocks per class in k1d
#define NSHARD  16            // sharded M accumulators

// ws layout (4-byte units)
#define OFF_CNT  0                         // [16] int
#define OFF_PADO 16                        // [16] int
#define OFF_LDC  32                        // [16] float
#define OFF_PM   48                        // [48] float
#define OFF_PL   96                        // [48] float
#define OFF_MU   144                       // [640] float
#define OFF_SC   784                       // [10][4096] float
#define OFF_S    41744                     // [640] float, atomic accum  (zeroed)
#define OFF_MS   42384                     // [10][16][4096] float shards (zeroed)
#define OFF_HB   697744                    // [10][512] int
#define OFF_SIDX 702864                    // [N+640] int
#define ZERO_LO  OFF_S
#define ZERO_HI  (OFF_MS + NCLASS*NSHARD*4096)

typedef short  s8v  __attribute__((ext_vector_type(8)));
typedef short  s4v  __attribute__((ext_vector_type(4)));
typedef float  f16v __attribute__((ext_vector_type(16)));

__device__ __forceinline__ float rlane(float v, int l) {
  return __int_as_float(__builtin_amdgcn_readlane(__float_as_int(v), l));
}
__device__ __forceinline__ unsigned short f2bf(float x) {   // RNE to bf16
  union { float f; unsigned u; } v; v.f = x;
  unsigned r = v.u + 0x7fffu + ((v.u >> 16) & 1u);
  return (unsigned short)(r >> 16);
}
__device__ __forceinline__ float bf2f(unsigned short b) {
  union { float f; unsigned u; } v; v.u = ((unsigned)b) << 16;
  return v.f;
}

// ---------------------------------------------------------------- k1a: zero + per-chunk hist
__global__ __launch_bounds__(256) void k1a_hist(const int* __restrict__ T,
                                                float* __restrict__ ws, int N, int nchunk) {
  const int b = blockIdx.x, t = threadIdx.x;
  for (int z = ZERO_LO + b * 256 + t; z < ZERO_HI; z += nchunk * 256) ws[z] = 0.0f;
  __shared__ int h[NCLASS];
  if (t < NCLASS) h[t] = 0;
  __syncthreads();
  int start = b * CHUNK;
#pragma unroll
  for (int u = 0; u < 4; ++u) {
    int i = start + u * 256 + t;
    if (i < N) atomicAdd(&h[T[i]], 1);
  }
  __syncthreads();
  if (t < NCLASS) ((int*)(ws + OFF_HB))[t * NCHUNK_MAX + b] = h[t];
}

// ---------------------------------------------------------------- k1b: parallel scan -> bases
__global__ __launch_bounds__(640) void k1b_scan(float* __restrict__ ws, int nchunk) {
  const int w = threadIdx.x >> 6;
  const int l = threadIdx.x & 63;
  int* Hg = (int*)(ws + OFF_HB);
  __shared__ int tot[NCLASS];
  int v[8], pre[8];
  int lanesum = 0;
#pragma unroll
  for (int u = 0; u < 8; ++u) {
    int b = l * 8 + u;
    v[u] = (b < nchunk) ? Hg[w * NCHUNK_MAX + b] : 0;
    pre[u] = lanesum;
    lanesum += v[u];
  }
  int incl = lanesum;
#pragma unroll
  for (int off = 1; off < 64; off <<= 1) {
    int t2 = __shfl_up(incl, off, 64);
    if (l >= off) incl += t2;
  }
  int excl = incl - lanesum;
  int ctot = __shfl(incl, 63, 64);
  if (l == 0) tot[w] = ctot;
  __syncthreads();
  int pado = 0;
#pragma unroll
  for (int c = 0; c < NCLASS; ++c)
    if (c < w) pado += (tot[c] + 63) & ~63;
#pragma unroll
  for (int u = 0; u < 8; ++u) {
    int b = l * 8 + u;
    if (b < nchunk) Hg[w * NCHUNK_MAX + b] = pado + excl + pre[u];
  }
  if (l == 0) {
    ((int*)(ws + OFF_CNT))[w] = ctot;
    ((int*)(ws + OFF_PADO))[w] = pado;
    if (w == NCLASS - 1) ((int*)(ws + OFF_PADO))[NCLASS] = pado + ((ctot + 63) & ~63);
  }
}

// ---------------------------------------------------------------- k1c: deterministic-base scatter
__global__ __launch_bounds__(256) void k1c_scatter(const int* __restrict__ T,
                                                   float* __restrict__ ws, int N) {
  __shared__ int lcnt[NCLASS], lbase[NCLASS];
  const int b = blockIdx.x, t = threadIdx.x;
  if (t < NCLASS) { lcnt[t] = 0; lbase[t] = ((const int*)(ws + OFF_HB))[t * NCHUNK_MAX + b]; }
  __syncthreads();
  int start = b * CHUNK;
  int tv[4], rk[4];
#pragma unroll
  for (int u = 0; u < 4; ++u) {
    int i = start + u * 256 + t;
    if (i < N) { tv[u] = T[i]; rk[u] = atomicAdd(&lcnt[tv[u]], 1); }
    else tv[u] = -1;
  }
  __syncthreads();
  int* sidx = (int*)(ws + OFF_SIDX);
#pragma unroll
  for (int u = 0; u < 4; ++u)
    if (tv[u] >= 0) sidx[lbase[tv[u]] + rk[u]] = start + u * 256 + t;
}

// ---------------------------------------------------------------- k1d: MFMA split-bf16 Gram
// G = H'H + H'L + (H'L)'  (LL ~2^-18, dropped). acc1 = H'H, acc2 = H'L:
// 8 MFMAs + 12 b128 reads per 64-row batch. 2-deep prefetch pipeline.
__global__ __launch_bounds__(256, 4) void k1d_gram(const float* __restrict__ X,
                                                   float* __restrict__ ws) {
  __shared__ __align__(16) short Ab[2][2][64 * 72];   // [dbuf][hi/lo][feat*72+row'] 36864B
  const int c    = blockIdx.y;
  const int t    = threadIdx.x;
  const int w    = t >> 6, lane = t & 63;
  const int wi   = w >> 1, wj = w & 1;
  const int mcol = lane & 31, khalf = lane >> 5;
  const int rq   = t >> 4, fq = t & 15;      // staging: row-quad, feat-quad
  const int cnt  = ((const int*)(ws + OFF_CNT))[c];
  const int base = ((const int*)(ws + OFF_PADO))[c];
  const int* __restrict__ sidx = (const int*)(ws + OFF_SIDX);
  const float4* __restrict__ X4 = (const float4*)X;
  const int nmb = (cnt + 63) >> 6;
  const int mb0 = blockIdx.x;

  f16v acc1 = {}, acc2 = {};
  float csum[4] = {0.f, 0.f, 0.f, 0.f};
  float4 pv[2][4];

#define LOADB(bi, dst)                                                   \
  {                                                                      \
    int b_ = mb0 + (bi) * K1D_BPC;                                       \
    _Pragma("unroll")                                                    \
    for (int j = 0; j < 4; ++j) {                                        \
      int p_ = (b_ << 6) + rq * 4 + j;                                   \
      float4 v_ = {0.f, 0.f, 0.f, 0.f};                                  \
      if (b_ < nmb && p_ < cnt) v_ = X4[(size_t)sidx[base + p_] * 16 + fq]; \
      (dst)[j] = v_;                                                     \
    }                                                                    \
  }
#define CONVB(src, dbuf)                                                 \
  {                                                                      \
    short* hi_ = &Ab[dbuf][0][0];                                        \
    short* lo_ = &Ab[dbuf][1][0];                                        \
    _Pragma("unroll")                                                    \
    for (int e = 0; e < 4; ++e) {                                        \
      int f_ = fq * 4 + e;                                               \
      float x0 = (&(src)[0].x)[e], x1 = (&(src)[1].x)[e];                \
      float x2 = (&(src)[2].x)[e], x3 = (&(src)[3].x)[e];                \
      csum[e] += x0 + x1 + x2 + x3;                                      \
      unsigned short h0 = f2bf(x0), h1 = f2bf(x1), h2 = f2bf(x2), h3 = f2bf(x3); \
      s4v hv = {(short)h0, (short)h1, (short)h2, (short)h3};             \
      s4v lv = {(short)f2bf(x0 - bf2f(h0)), (short)f2bf(x1 - bf2f(h1)),  \
                (short)f2bf(x2 - bf2f(h2)), (short)f2bf(x3 - bf2f(h3))}; \
      int off_ = f_ * 72 + (((rq >> 1) ^ (f_ >> 3)) << 3) + ((rq & 1) << 2); \
      *(s4v*)(hi_ + off_) = hv;                                          \
      *(s4v*)(lo_ + off_) = lv;                                          \
    }                                                                    \
  }

  int nb_blk = (nmb > mb0) ? ((nmb - mb0 + K1D_BPC - 1) / K1D_BPC) : 0;

  LOADB(0, pv[0]);
  CONVB(pv[0], 0);
  LOADB(1, pv[0]);

  const int fA = wi * 32 + mcol;
  const int fB = wj * 32 + mcol;
  const int offA0 = fA * 72, offB0 = fB * 72;
  const int swA = fA >> 3, swB = fB >> 3;

  for (int i = 0; i < nb_blk; ++i) {
    LOADB(i + 2, pv[(i + 1) & 1]);          // 2-deep prefetch
    __syncthreads();                         // buf[i&1] writes visible
    {
      const short* hi = &Ab[i & 1][0][0];
      const short* lo = &Ab[i & 1][1][0];
#pragma unroll
      for (int ks = 0; ks < 4; ++ks) {
        int rb = ks * 2 + khalf;
        s8v aH = *(const s8v*)(hi + offA0 + ((rb ^ swA) << 3));
        s8v bH = *(const s8v*)(hi + offB0 + ((rb ^ swB) << 3));
        s8v bL = *(const s8v*)(lo + offB0 + ((rb ^ swB) << 3));
        acc1 = __builtin_amdgcn_mfma_f32_32x32x16_bf16(aH, bH, acc1, 0, 0, 0);
        acc2 = __builtin_amdgcn_mfma_f32_32x32x16_bf16(aH, bL, acc2, 0, 0, 0);
      }
    }
    CONVB(pv[i & 1], (i + 1) & 1);          // convert batch i+1 (loaded last iter)
  }
  __syncthreads();

  float* R    = (float*)&Ab[0][0][0];        // 64*65 floats, stride 65
  float* colp = R + 4224;
  *(float4*)&colp[rq * 64 + fq * 4] = *(float4*)csum;
#pragma unroll
  for (int r = 0; r < 16; ++r) {
    int fr = wi * 32 + (r & 3) + 8 * (r >> 2) + 4 * khalf;
    R[fr * 65 + fB] = acc1[r] + acc2[r];
  }
  __syncthreads();
#pragma unroll
  for (int r = 0; r < 16; ++r) {
    int fr = wi * 32 + (r & 3) + 8 * (r >> 2) + 4 * khalf;
    R[fB * 65 + fr] += acc2[r];
  }
  __syncthreads();

  float* Msh = ws + OFF_MS + (size_t)(c * NSHARD + (blockIdx.x & (NSHARD - 1))) * 4096;
  for (int e = t; e < 4096; e += 256)
    atomicAdd(&Msh[e], R[(e >> 6) * 65 + (e & 63)]);
  if (t < 64) {
    float s = 0.0f;
#pragma unroll
    for (int g = 0; g < 16; ++g) s += colp[g * 64 + t];
    atomicAdd(&ws[OFF_S + c * 64 + t], s);
  }
#undef LOADB
#undef CONVB
}

// ---------------------------------------------------------------- k1e: reduce shards -> mu, Sc
__global__ __launch_bounds__(256) void k1e_cov(float* __restrict__ ws) {
  const int c = blockIdx.x, t = threadIdx.x;
  __shared__ float mu[64];
  float cnt = (float)((const int*)(ws + OFF_CNT))[c];
  if (t < 64) {
    float m = ws[OFF_S + c * 64 + t] / cnt;
    mu[t] = m;
    ws[OFF_MU + c * 64 + t] = m;
  }
  __syncthreads();
  float inv = 1.0f / (cnt - 1.0f);
  const float* Ms = ws + OFF_MS + (size_t)c * NSHARD * 4096;
  for (int e = t; e < 4096; e += 256) {
    float s = 0.0f;
#pragma unroll
    for (int sh = 0; sh < NSHARD; ++sh) s += Ms[sh * 4096 + e];
    int r = e >> 6, l = e & 63;
    ws[OFF_SC + c * 4096 + e] = (s - cnt * mu[r] * mu[l]) * inv;
  }
}

// ---------------------------------------------------------------- k2b: register Cholesky
// KERNEL RULE: __launch_bounds__(64, 1) is REQUIRED. With a bare (64), the
// allocator's occupancy heuristic sits exactly at the S[64]-fits boundary and
// unrelated TU changes flip it into scratch-spilling (R6: 143us, R9: 148us,
// both VGPR_Count=72). (64,1) grants the full ~512-VGPR budget: 55 single-wave
// blocks don't need occupancy; the kernel is serial-chain latency-bound.
__global__ __launch_bounds__(64, 1) void k2b_chol(float* __restrict__ ws) {
  __shared__ float Sld[64][65];
  const int lane = threadIdx.x;
  const int bid  = blockIdx.x;

  int ci, cj, p = -1;
  bool isPair = (bid >= NCLASS);
  if (!isPair) { ci = cj = bid; }
  else {
    p = bid - NCLASS;
    int rem = p, i = 0;
    while (rem >= 9 - i) { rem -= 9 - i; ++i; }
    ci = i; cj = i + 1 + rem;
  }

  const float* A = ws + OFF_SC + ci * 4096;
  const float* B = ws + OFF_SC + cj * 4096;
  for (int r = 0; r < 64; ++r) {
    float v = A[r * 64 + lane];
    if (isPair) v = 0.5f * (v + B[r * 64 + lane]);
    Sld[r][lane] = v;
  }
  float pi = isPair ? (ws[OFF_MU + ci * 64 + lane] - ws[OFF_MU + cj * 64 + lane]) : 0.0f;
  __syncthreads();

  float S[64];
#pragma unroll
  for (int q = 0; q < 16; ++q)
    *(float4*)&S[q * 4] = *(const float4*)&Sld[lane][q * 4];

  float logacc = 0.0f, s2 = 0.0f;
#pragma unroll
  for (int k = 0; k < 64; ++k) {
    float lkk = sqrtf(rlane(S[k], k));
    float inv = 1.0f / lkk;
    float lik = S[k] * inv;
    S[k] = lik;
    logacc += logf(lkk);
    float yk = rlane(pi, k) * inv;
    s2 += yk * yk;
    pi -= (lane > k) ? lik * yk : 0.0f;
#pragma unroll
    for (int j = k + 1; j < 64; ++j)
      S[j] -= lik * rlane(lik, j);
  }

  if (lane == 0) {
    if (isPair) {
      ws[OFF_PM + p] = s2 * 0.125f;
      ws[OFF_PL + p] = 2.0f * logacc;
    } else {
      ws[OFF_LDC + bid] = 2.0f * logacc;
    }
  }
}

// ---------------------------------------------------------------- k2c: final scalar
__global__ void k2c_final(const float* __restrict__ Ksamp,
                          const float* __restrict__ ws,
                          float* __restrict__ out) {
  __shared__ float ldc[10], pm[45], pl[45];
  __shared__ float Km[100], Sp[100], L[100], Inv[100], Aa[100];
  __shared__ float red[3];
  const int tid = threadIdx.x;
  const int k = 10;

  if (tid < 3) red[tid] = 0.0f;
  if (tid < 10) ldc[tid] = ws[OFF_LDC + tid];
  if (tid < 45) { pm[tid] = ws[OFF_PM + tid]; pl[tid] = ws[OFF_PL + tid]; }
  if (tid < 100) Sp[tid] = Ksamp[tid];
  __syncthreads();

  float s00 = Sp[0];
  if (tid < 100) {
    int i = tid / 10, j = tid % 10;
    float Kv;
    if (i == j) Kv = s00;
    else {
      int a = i < j ? i : j, b = i < j ? j : i;
      int pp = (a * (19 - a)) / 2 + (b - a - 1);
      float D = pm[pp] + 0.5f * (pl[pp] - 0.5f * (ldc[i] + ldc[j]));
      Kv = s00 * 0.5f * expf(-D * D * 100.0f);
    }
    Km[tid] = Kv;
    Aa[tid] = Kv;
  }
  __syncthreads();

  for (int kk = 0; kk < k; ++kk) {
    if (tid == kk) {
      float s = Sp[kk * k + kk];
      for (int m = 0; m < kk; ++m) s -= L[kk * k + m] * L[kk * k + m];
      L[kk * k + kk] = sqrtf(s);
    }
    __syncthreads();
    if (tid > kk && tid < k) {
      float v = Sp[tid * k + kk];
      for (int m = 0; m < kk; ++m) v -= L[tid * k + m] * L[kk * k + m];
      L[tid * k + kk] = v / L[kk * k + kk];
    }
    __syncthreads();
  }
  if (tid < k) atomicAdd(&red[0], 2.0f * logf(L[tid * k + tid]));

  if (tid < k) {
    float y[10], x[10];
    for (int r = 0; r < k; ++r) {
      float v = (r == tid) ? 1.0f : 0.0f;
      for (int m = 0; m < r; ++m) v -= L[r * k + m] * y[m];
      y[r] = v / L[r * k + r];
    }
    for (int r = k - 1; r >= 0; --r) {
      float v = y[r];
      for (int m = r + 1; m < k; ++m) v -= L[m * k + r] * x[m];
      x[r] = v / L[r * k + r];
    }
    for (int r = 0; r < k; ++r) Inv[r * k + tid] = x[r];
  }
  __syncthreads();
  if (tid < 100) atomicAdd(&red[1], Inv[tid] * Km[tid]);

  for (int kk = 0; kk < k; ++kk) {
    if (tid == 0) {
      int piv = kk; float mx = fabsf(Aa[kk * k + kk]);
      for (int r = kk + 1; r < k; ++r) {
        float v = fabsf(Aa[r * k + kk]);
        if (v > mx) { mx = v; piv = r; }
      }
      if (piv != kk)
        for (int c2 = 0; c2 < k; ++c2) {
          float tmp = Aa[kk * k + c2]; Aa[kk * k + c2] = Aa[piv * k + c2]; Aa[piv * k + c2] = tmp;
        }
      red[2] += logf(fabsf(Aa[kk * k + kk]));
    }
    __syncthreads();
    if (tid < 100) {
      int r = tid / 10, c2 = tid % 10;
      if (r > kk && c2 > kk)
        Aa[r * k + c2] -= Aa[r * k + kk] / Aa[kk * k + kk] * Aa[kk * k + c2];
    }
    __syncthreads();
  }

  if (tid == 0)
    out[0] = 0.5f * (red[1] - (float)k + red[0] - red[2]);
}

// ---------------------------------------------------------------- launch
extern "C" void kernel_launch(void* const* d_in, const int* in_sizes, int n_in,
                              void* d_out, int out_size, void* d_ws, size_t ws_size,
                              hipStream_t stream) {
  const float* X  = (const float*)d_in[0];
  const int*   T  = (const int*)d_in[1];
  const float* Ks = (const float*)d_in[2];
  float* out = (float*)d_out;
  float* ws  = (float*)d_ws;
  int N = in_sizes[1];
  int nchunk = (N + CHUNK - 1) / CHUNK;

  k1a_hist<<<nchunk, 256, 0, stream>>>(T, ws, N, nchunk);
  k1b_scan<<<1, 640, 0, stream>>>(ws, nchunk);
  k1c_scatter<<<nchunk, 256, 0, stream>>>(T, ws, N);
  k1d_gram<<<dim3(K1D_BPC, NCLASS), 256, 0, stream>>>(X, ws);
  k1e_cov<<<NCLASS, 256, 0, stream>>>(ws);
  k2b_chol<<<55, 64, 0, stream>>>(ws);
  k2c_final<<<1, 128, 0, stream>>>(Ks, ws, out);
}

// Round 11
// 360.958 us; speedup vs baseline: 1.2860x; 1.0010x over previous
//
#include <hip/hip_runtime.h>
#include <math.h>

#define NCLASS  10
#define NFEAT   64
#define CHUNK   1024          // rows per hist/scatter chunk
#define NCHUNK_MAX 512        // N=524288 -> 512 chunks
#define K1D_BPC 104           // blocks per class in k1d
#define NSHARD  16            // sharded M accumulators

// ws layout (4-byte units)
#define OFF_CNT  0                         // [16] int
#define OFF_PADO 16                        // [16] int
#define OFF_LDC  32                        // [16] float
#define OFF_PM   48                        // [48] float
#define OFF_PL   96                        // [48] float
#define OFF_MU   144                       // [640] float
#define OFF_SC   784                       // [10][4096] float
#define OFF_S    41744                     // [640] float, atomic accum  (zeroed)
#define OFF_MS   42384                     // [10][16][4096] float shards (zeroed)
#define OFF_HB   697744                    // [10][512] int
#define OFF_SIDX 702864                    // [N+640] int
#define ZERO_LO  OFF_S
#define ZERO_HI  (OFF_MS + NCLASS*NSHARD*4096)

typedef short  s8v  __attribute__((ext_vector_type(8)));
typedef short  s4v  __attribute__((ext_vector_type(4)));
typedef float  f16v __attribute__((ext_vector_type(16)));

__device__ __forceinline__ float rlane(float v, int l) {
  return __int_as_float(__builtin_amdgcn_readlane(__float_as_int(v), l));
}
__device__ __forceinline__ unsigned short f2bf(float x) {   // RNE to bf16
  union { float f; unsigned u; } v; v.f = x;
  unsigned r = v.u + 0x7fffu + ((v.u >> 16) & 1u);
  return (unsigned short)(r >> 16);
}
__device__ __forceinline__ float bf2f(unsigned short b) {
  union { float f; unsigned u; } v; v.u = ((unsigned)b) << 16;
  return v.f;
}

// ---------------------------------------------------------------- k1a: zero + per-chunk hist
__global__ __launch_bounds__(256) void k1a_hist(const int* __restrict__ T,
                                                float* __restrict__ ws, int N, int nchunk) {
  const int b = blockIdx.x, t = threadIdx.x;
  for (int z = ZERO_LO + b * 256 + t; z < ZERO_HI; z += nchunk * 256) ws[z] = 0.0f;
  __shared__ int h[NCLASS];
  if (t < NCLASS) h[t] = 0;
  __syncthreads();
  int start = b * CHUNK;
#pragma unroll
  for (int u = 0; u < 4; ++u) {
    int i = start + u * 256 + t;
    if (i < N) atomicAdd(&h[T[i]], 1);
  }
  __syncthreads();
  if (t < NCLASS) ((int*)(ws + OFF_HB))[t * NCHUNK_MAX + b] = h[t];
}

// ---------------------------------------------------------------- k1b: parallel scan -> bases
__global__ __launch_bounds__(640) void k1b_scan(float* __restrict__ ws, int nchunk) {
  const int w = threadIdx.x >> 6;
  const int l = threadIdx.x & 63;
  int* Hg = (int*)(ws + OFF_HB);
  __shared__ int tot[NCLASS];
  int v[8], pre[8];
  int lanesum = 0;
#pragma unroll
  for (int u = 0; u < 8; ++u) {
    int b = l * 8 + u;
    v[u] = (b < nchunk) ? Hg[w * NCHUNK_MAX + b] : 0;
    pre[u] = lanesum;
    lanesum += v[u];
  }
  int incl = lanesum;
#pragma unroll
  for (int off = 1; off < 64; off <<= 1) {
    int t2 = __shfl_up(incl, off, 64);
    if (l >= off) incl += t2;
  }
  int excl = incl - lanesum;
  int ctot = __shfl(incl, 63, 64);
  if (l == 0) tot[w] = ctot;
  __syncthreads();
  int pado = 0;
#pragma unroll
  for (int c = 0; c < NCLASS; ++c)
    if (c < w) pado += (tot[c] + 63) & ~63;
#pragma unroll
  for (int u = 0; u < 8; ++u) {
    int b = l * 8 + u;
    if (b < nchunk) Hg[w * NCHUNK_MAX + b] = pado + excl + pre[u];
  }
  if (l == 0) {
    ((int*)(ws + OFF_CNT))[w] = ctot;
    ((int*)(ws + OFF_PADO))[w] = pado;
    if (w == NCLASS - 1) ((int*)(ws + OFF_PADO))[NCLASS] = pado + ((ctot + 63) & ~63);
  }
}

// ---------------------------------------------------------------- k1c: deterministic-base scatter
__global__ __launch_bounds__(256) void k1c_scatter(const int* __restrict__ T,
                                                   float* __restrict__ ws, int N) {
  __shared__ int lcnt[NCLASS], lbase[NCLASS];
  const int b = blockIdx.x, t = threadIdx.x;
  if (t < NCLASS) { lcnt[t] = 0; lbase[t] = ((const int*)(ws + OFF_HB))[t * NCHUNK_MAX + b]; }
  __syncthreads();
  int start = b * CHUNK;
  int tv[4], rk[4];
#pragma unroll
  for (int u = 0; u < 4; ++u) {
    int i = start + u * 256 + t;
    if (i < N) { tv[u] = T[i]; rk[u] = atomicAdd(&lcnt[tv[u]], 1); }
    else tv[u] = -1;
  }
  __syncthreads();
  int* sidx = (int*)(ws + OFF_SIDX);
#pragma unroll
  for (int u = 0; u < 4; ++u)
    if (tv[u] >= 0) sidx[lbase[tv[u]] + rk[u]] = start + u * 256 + t;
}

// ---------------------------------------------------------------- k1d: MFMA split-bf16 Gram
// G = H'H + H'L + (H'L)'  (LL ~2^-18, dropped). acc1 = H'H, acc2 = H'L:
// 8 MFMAs + 12 b128 reads per 64-row batch. 2-deep prefetch pipeline.
// KERNEL RULE: __launch_bounds__(256, 2) REQUIRED — live state ~100 VGPRs
// (acc1 16 + acc2 16 + pv[2][4] 32 + addr). At (256,4) the allocator capped
// VGPR_Count=64 and spilled pv to scratch: WRITE_SIZE 17->177 MB, 142us (R10).
// (256,2) grants 256 VGPR/wave; 2 blocks/CU occupancy is enough.
__global__ __launch_bounds__(256, 2) void k1d_gram(const float* __restrict__ X,
                                                   float* __restrict__ ws) {
  __shared__ __align__(16) short Ab[2][2][64 * 72];   // [dbuf][hi/lo][feat*72+row'] 36864B
  const int c    = blockIdx.y;
  const int t    = threadIdx.x;
  const int w    = t >> 6, lane = t & 63;
  const int wi   = w >> 1, wj = w & 1;
  const int mcol = lane & 31, khalf = lane >> 5;
  const int rq   = t >> 4, fq = t & 15;      // staging: row-quad, feat-quad
  const int cnt  = ((const int*)(ws + OFF_CNT))[c];
  const int base = ((const int*)(ws + OFF_PADO))[c];
  const int* __restrict__ sidx = (const int*)(ws + OFF_SIDX);
  const float4* __restrict__ X4 = (const float4*)X;
  const int nmb = (cnt + 63) >> 6;
  const int mb0 = blockIdx.x;

  f16v acc1 = {}, acc2 = {};
  float csum[4] = {0.f, 0.f, 0.f, 0.f};
  float4 pv[2][4];

#define LOADB(bi, dst)                                                   \
  {                                                                      \
    int b_ = mb0 + (bi) * K1D_BPC;                                       \
    _Pragma("unroll")                                                    \
    for (int j = 0; j < 4; ++j) {                                        \
      int p_ = (b_ << 6) + rq * 4 + j;                                   \
      float4 v_ = {0.f, 0.f, 0.f, 0.f};                                  \
      if (b_ < nmb && p_ < cnt) v_ = X4[(size_t)sidx[base + p_] * 16 + fq]; \
      (dst)[j] = v_;                                                     \
    }                                                                    \
  }
#define CONVB(src, dbuf)                                                 \
  {                                                                      \
    short* hi_ = &Ab[dbuf][0][0];                                        \
    short* lo_ = &Ab[dbuf][1][0];                                        \
    _Pragma("unroll")                                                    \
    for (int e = 0; e < 4; ++e) {                                        \
      int f_ = fq * 4 + e;                                               \
      float x0 = (&(src)[0].x)[e], x1 = (&(src)[1].x)[e];                \
      float x2 = (&(src)[2].x)[e], x3 = (&(src)[3].x)[e];                \
      csum[e] += x0 + x1 + x2 + x3;                                      \
      unsigned short h0 = f2bf(x0), h1 = f2bf(x1), h2 = f2bf(x2), h3 = f2bf(x3); \
      s4v hv = {(short)h0, (short)h1, (short)h2, (short)h3};             \
      s4v lv = {(short)f2bf(x0 - bf2f(h0)), (short)f2bf(x1 - bf2f(h1)),  \
                (short)f2bf(x2 - bf2f(h2)), (short)f2bf(x3 - bf2f(h3))}; \
      int off_ = f_ * 72 + (((rq >> 1) ^ (f_ >> 3)) << 3) + ((rq & 1) << 2); \
      *(s4v*)(hi_ + off_) = hv;                                          \
      *(s4v*)(lo_ + off_) = lv;                                          \
    }                                                                    \
  }

  int nb_blk = (nmb > mb0) ? ((nmb - mb0 + K1D_BPC - 1) / K1D_BPC) : 0;

  LOADB(0, pv[0]);
  CONVB(pv[0], 0);
  LOADB(1, pv[0]);

  const int fA = wi * 32 + mcol;
  const int fB = wj * 32 + mcol;
  const int offA0 = fA * 72, offB0 = fB * 72;
  const int swA = fA >> 3, swB = fB >> 3;

  for (int i = 0; i < nb_blk; ++i) {
    LOADB(i + 2, pv[(i + 1) & 1]);          // 2-deep prefetch
    __syncthreads();                         // buf[i&1] writes visible
    {
      const short* hi = &Ab[i & 1][0][0];
      const short* lo = &Ab[i & 1][1][0];
#pragma unroll
      for (int ks = 0; ks < 4; ++ks) {
        int rb = ks * 2 + khalf;
        s8v aH = *(const s8v*)(hi + offA0 + ((rb ^ swA) << 3));
        s8v bH = *(const s8v*)(hi + offB0 + ((rb ^ swB) << 3));
        s8v bL = *(const s8v*)(lo + offB0 + ((rb ^ swB) << 3));
        acc1 = __builtin_amdgcn_mfma_f32_32x32x16_bf16(aH, bH, acc1, 0, 0, 0);
        acc2 = __builtin_amdgcn_mfma_f32_32x32x16_bf16(aH, bL, acc2, 0, 0, 0);
      }
    }
    CONVB(pv[i & 1], (i + 1) & 1);          // convert batch i+1 (loaded last iter)
  }
  __syncthreads();

  float* R    = (float*)&Ab[0][0][0];        // 64*65 floats, stride 65
  float* colp = R + 4224;
  *(float4*)&colp[rq * 64 + fq * 4] = *(float4*)csum;
#pragma unroll
  for (int r = 0; r < 16; ++r) {
    int fr = wi * 32 + (r & 3) + 8 * (r >> 2) + 4 * khalf;
    R[fr * 65 + fB] = acc1[r] + acc2[r];
  }
  __syncthreads();
#pragma unroll
  for (int r = 0; r < 16; ++r) {
    int fr = wi * 32 + (r & 3) + 8 * (r >> 2) + 4 * khalf;
    R[fB * 65 + fr] += acc2[r];
  }
  __syncthreads();

  float* Msh = ws + OFF_MS + (size_t)(c * NSHARD + (blockIdx.x & (NSHARD - 1))) * 4096;
  for (int e = t; e < 4096; e += 256)
    atomicAdd(&Msh[e], R[(e >> 6) * 65 + (e & 63)]);
  if (t < 64) {
    float s = 0.0f;
#pragma unroll
    for (int g = 0; g < 16; ++g) s += colp[g * 64 + t];
    atomicAdd(&ws[OFF_S + c * 64 + t], s);
  }
#undef LOADB
#undef CONVB
}

// ---------------------------------------------------------------- k1e: reduce shards -> mu, Sc
__global__ __launch_bounds__(256) void k1e_cov(float* __restrict__ ws) {
  const int c = blockIdx.x, t = threadIdx.x;
  __shared__ float mu[64];
  float cnt = (float)((const int*)(ws + OFF_CNT))[c];
  if (t < 64) {
    float m = ws[OFF_S + c * 64 + t] / cnt;
    mu[t] = m;
    ws[OFF_MU + c * 64 + t] = m;
  }
  __syncthreads();
  float inv = 1.0f / (cnt - 1.0f);
  const float* Ms = ws + OFF_MS + (size_t)c * NSHARD * 4096;
  for (int e = t; e < 4096; e += 256) {
    float s = 0.0f;
#pragma unroll
    for (int sh = 0; sh < NSHARD; ++sh) s += Ms[sh * 4096 + e];
    int r = e >> 6, l = e & 63;
    ws[OFF_SC + c * 4096 + e] = (s - cnt * mu[r] * mu[l]) * inv;
  }
}

// ---------------------------------------------------------------- k2b: register Cholesky
// KERNEL RULE: __launch_bounds__(64, 1) is REQUIRED. With a bare (64), the
// allocator's occupancy heuristic sits exactly at the S[64]-fits boundary and
// unrelated TU changes flip it into scratch-spilling (R6: 143us, R9: 148us,
// both VGPR_Count=72). (64,1) grants the full ~512-VGPR budget: 55 single-wave
// blocks don't need occupancy; the kernel is serial-chain latency-bound.
__global__ __launch_bounds__(64, 1) void k2b_chol(float* __restrict__ ws) {
  __shared__ float Sld[64][65];
  const int lane = threadIdx.x;
  const int bid  = blockIdx.x;

  int ci, cj, p = -1;
  bool isPair = (bid >= NCLASS);
  if (!isPair) { ci = cj = bid; }
  else {
    p = bid - NCLASS;
    int rem = p, i = 0;
    while (rem >= 9 - i) { rem -= 9 - i; ++i; }
    ci = i; cj = i + 1 + rem;
  }

  const float* A = ws + OFF_SC + ci * 4096;
  const float* B = ws + OFF_SC + cj * 4096;
  for (int r = 0; r < 64; ++r) {
    float v = A[r * 64 + lane];
    if (isPair) v = 0.5f * (v + B[r * 64 + lane]);
    Sld[r][lane] = v;
  }
  float pi = isPair ? (ws[OFF_MU + ci * 64 + lane] - ws[OFF_MU + cj * 64 + lane]) : 0.0f;
  __syncthreads();

  float S[64];
#pragma unroll
  for (int q = 0; q < 16; ++q)
    *(float4*)&S[q * 4] = *(const float4*)&Sld[lane][q * 4];

  float logacc = 0.0f, s2 = 0.0f;
#pragma unroll
  for (int k = 0; k < 64; ++k) {
    float lkk = sqrtf(rlane(S[k], k));
    float inv = 1.0f / lkk;
    float lik = S[k] * inv;
    S[k] = lik;
    logacc += logf(lkk);
    float yk = rlane(pi, k) * inv;
    s2 += yk * yk;
    pi -= (lane > k) ? lik * yk : 0.0f;
#pragma unroll
    for (int j = k + 1; j < 64; ++j)
      S[j] -= lik * rlane(lik, j);
  }

  if (lane == 0) {
    if (isPair) {
      ws[OFF_PM + p] = s2 * 0.125f;
      ws[OFF_PL + p] = 2.0f * logacc;
    } else {
      ws[OFF_LDC + bid] = 2.0f * logacc;
    }
  }
}

// ---------------------------------------------------------------- k2c: final scalar
__global__ void k2c_final(const float* __restrict__ Ksamp,
                          const float* __restrict__ ws,
                          float* __restrict__ out) {
  __shared__ float ldc[10], pm[45], pl[45];
  __shared__ float Km[100], Sp[100], L[100], Inv[100], Aa[100];
  __shared__ float red[3];
  const int tid = threadIdx.x;
  const int k = 10;

  if (tid < 3) red[tid] = 0.0f;
  if (tid < 10) ldc[tid] = ws[OFF_LDC + tid];
  if (tid < 45) { pm[tid] = ws[OFF_PM + tid]; pl[tid] = ws[OFF_PL + tid]; }
  if (tid < 100) Sp[tid] = Ksamp[tid];
  __syncthreads();

  float s00 = Sp[0];
  if (tid < 100) {
    int i = tid / 10, j = tid % 10;
    float Kv;
    if (i == j) Kv = s00;
    else {
      int a = i < j ? i : j, b = i < j ? j : i;
      int pp = (a * (19 - a)) / 2 + (b - a - 1);
      float D = pm[pp] + 0.5f * (pl[pp] - 0.5f * (ldc[i] + ldc[j]));
      Kv = s00 * 0.5f * expf(-D * D * 100.0f);
    }
    Km[tid] = Kv;
    Aa[tid] = Kv;
  }
  __syncthreads();

  for (int kk = 0; kk < k; ++kk) {
    if (tid == kk) {
      float s = Sp[kk * k + kk];
      for (int m = 0; m < kk; ++m) s -= L[kk * k + m] * L[kk * k + m];
      L[kk * k + kk] = sqrtf(s);
    }
    __syncthreads();
    if (tid > kk && tid < k) {
      float v = Sp[tid * k + kk];
      for (int m = 0; m < kk; ++m) v -= L[tid * k + m] * L[kk * k + m];
      L[tid * k + kk] = v / L[kk * k + kk];
    }
    __syncthreads();
  }
  if (tid < k) atomicAdd(&red[0], 2.0f * logf(L[tid * k + tid]));

  if (tid < k) {
    float y[10], x[10];
    for (int r = 0; r < k; ++r) {
      float v = (r == tid) ? 1.0f : 0.0f;
      for (int m = 0; m < r; ++m) v -= L[r * k + m] * y[m];
      y[r] = v / L[r * k + r];
    }
    for (int r = k - 1; r >= 0; --r) {
      float v = y[r];
      for (int m = r + 1; m < k; ++m) v -= L[m * k + r] * x[m];
      x[r] = v / L[r * k + r];
    }
    for (int r = 0; r < k; ++r) Inv[r * k + tid] = x[r];
  }
  __syncthreads();
  if (tid < 100) atomicAdd(&red[1], Inv[tid] * Km[tid]);

  for (int kk = 0; kk < k; ++kk) {
    if (tid == 0) {
      int piv = kk; float mx = fabsf(Aa[kk * k + kk]);
      for (int r = kk + 1; r < k; ++r) {
        float v = fabsf(Aa[r * k + kk]);
        if (v > mx) { mx = v; piv = r; }
      }
      if (piv != kk)
        for (int c2 = 0; c2 < k; ++c2) {
          float tmp = Aa[kk * k + c2]; Aa[kk * k + c2] = Aa[piv * k + c2]; Aa[piv * k + c2] = tmp;
        }
      red[2] += logf(fabsf(Aa[kk * k + kk]));
    }
    __syncthreads();
    if (tid < 100) {
      int r = tid / 10, c2 = tid % 10;
      if (r > kk && c2 > kk)
        Aa[r * k + c2] -= Aa[r * k + kk] / Aa[kk * k + kk] * Aa[kk * k + c2];
    }
    __syncthreads();
  }

  if (tid == 0)
    out[0] = 0.5f * (red[1] - (float)k + red[0] - red[2]);
}

// ---------------------------------------------------------------- launch
extern "C" void kernel_launch(void* const* d_in, const int* in_sizes, int n_in,
                              void* d_out, int out_size, void* d_ws, size_t ws_size,
                              hipStream_t stream) {
  const float* X  = (const float*)d_in[0];
  const int*   T  = (const int*)d_in[1];
  const float* Ks = (const float*)d_in[2];
  float* out = (float*)d_out;
  float* ws  = (float*)d_ws;
  int N = in_sizes[1];
  int nchunk = (N + CHUNK - 1) / CHUNK;

  k1a_hist<<<nchunk, 256, 0, stream>>>(T, ws, N, nchunk);
  k1b_scan<<<1, 640, 0, stream>>>(ws, nchunk);
  k1c_scatter<<<nchunk, 256, 0, stream>>>(T, ws, N);
  k1d_gram<<<dim3(K1D_BPC, NCLASS), 256, 0, stream>>>(X, ws);
  k1e_cov<<<NCLASS, 256, 0, stream>>>(ws);
  k2b_chol<<<55, 64, 0, stream>>>(ws);
  k2c_final<<<1, 128, 0, stream>>>(Ks, ws, out);
}